// Round 1
// baseline (63.570 us; speedup 1.0000x reference)
//
#include <hip/hip_runtime.h>
#include <math.h>

#define OUT_LEN 512
#define NEED 257
#define T_IN 2048
#define C_CH 64

__global__ __launch_bounds__(256) void spectral_pool_kernel(
    const float* __restrict__ x, const int* __restrict__ length,
    float* __restrict__ out)
{
    const int bc  = blockIdx.x;
    const int b   = bc >> 6;          // / 64 channels
    const int tid = threadIdx.x;
    const int L   = length[b];

    const float* __restrict__ xrow = x + (size_t)bc * T_IN;
    float* __restrict__ orow = out + (size_t)bc * OUT_LEN;

    // ---- short-sequence branch: masked copy (uniform per block) ----
    if (L < OUT_LEN) {
        for (int t = tid; t < OUT_LEN; t += 256) {
            orow[t] = (t < L) ? xrow[t] : 0.0f;
        }
        return;
    }

    __shared__ float xs[T_IN];
    __shared__ float Xr[NEED];
    __shared__ float Xi[NEED];
    __shared__ float red[256];

    // ---- stage x row into LDS (coalesced float4) ----
    {
        const float4* __restrict__ src = (const float4*)xrow;
        float4* dst = (float4*)xs;
        #pragma unroll
        for (int i = 0; i < T_IN / 4 / 256; ++i)
            dst[tid + i * 256] = src[tid + i * 256];
    }
    __syncthreads();

    const float twoPi = 6.28318530717958647692f;
    const float fL = (float)L;

    // ---- forward DFT: bin k = tid (k = 0..255) ----
    // X_k = sum_{t<L} x_t * e^{-2*pi*i*k*t/L}, via incremental rotation.
    {
        const int k = tid;
        float s, co;
        sincosf(-twoPi * (float)k / fL, &s, &co);   // step rotator w = e^{-2pi i k/L}
        float zr = 1.0f, zi = 0.0f;                 // z = w^t, starts at t=0
        float ar = 0.0f, ai = 0.0f;
        for (int t = 0; t < L; ++t) {
            const float xv = xs[t];                 // broadcast read (conflict-free)
            ar = fmaf(xv, zr, ar);
            ai = fmaf(xv, zi, ai);
            const float nzr = fmaf(zr, co, -zi * s);
            const float nzi = fmaf(zr, s,   zi * co);
            zr = nzr; zi = nzi;
        }
        Xr[k] = ar;
        Xi[k] = ai;
    }

    // ---- Nyquist bin k=256: only Re needed by irfft ----
    {
        float part = 0.0f;
        for (int t = tid; t < L; t += 256) {
            const int m = (256 * t) % L;            // exact integer angle reduction
            part = fmaf(xs[t], cosf(-twoPi * (float)m / fL), part);
        }
        red[tid] = part;
    }
    __syncthreads();
    #pragma unroll
    for (int sft = 128; sft > 0; sft >>= 1) {
        if (tid < sft) red[tid] += red[tid + sft];
        __syncthreads();
    }
    if (tid == 0) { Xr[256] = red[0]; Xi[256] = 0.0f; }
    __syncthreads();

    // ---- inverse rfft (n = 512, norm = backward => scale 1/512) ----
    // out[t]     = (1/512)[Xr0 + (-1)^t Xr256 + 2*sum_{k=1}^{255} Re(X_k e^{2pi i k t/512})]
    // out[t+256] : same with extra (-1)^k per term (e^{i pi k}); parity of t unchanged.
    {
        const int t = tid;                          // t = 0..255, also covers t+256
        float s, co;
        sincosf(twoPi * (float)t / 512.0f, &s, &co); // w = e^{+2pi i t/512}
        float zr = co, zi = s;                       // z = w^k at k=1
        float accE = 0.0f, accO = 0.0f;              // even-k / odd-k partial sums
        #pragma unroll 2
        for (int k = 1; k < 256; ++k) {
            const float re = fmaf(Xr[k], zr, -Xi[k] * zi);  // broadcast reads
            if (k & 1) accO += re; else accE += re;
            const float nzr = fmaf(zr, co, -zi * s);
            const float nzi = fmaf(zr, s,   zi * co);
            zr = nzr; zi = nzi;
        }
        const float base = Xr[0] + ((t & 1) ? -Xr[256] : Xr[256]);
        const float invN = 1.0f / 512.0f;
        orow[t]       = (base + 2.0f * (accE + accO)) * invN;
        orow[t + 256] = (base + 2.0f * (accE - accO)) * invN;
    }
}

extern "C" void kernel_launch(void* const* d_in, const int* in_sizes, int n_in,
                              void* d_out, int out_size, void* d_ws, size_t ws_size,
                              hipStream_t stream) {
    const float* x      = (const float*)d_in[0];
    const int*   length = (const int*)d_in[1];
    float*       out    = (float*)d_out;

    const int B = in_sizes[1];          // length has one entry per batch
    const int nblocks = B * C_CH;       // one block per (b, c) row

    hipLaunchKernelGGL(spectral_pool_kernel, dim3(nblocks), dim3(256), 0, stream,
                       x, length, out);
}

// Round 2
// 57.282 us; speedup vs baseline: 1.1098x; 1.1098x over previous
//
#include <hip/hip_runtime.h>
#include <math.h>

#define OUT_LEN 512
#define NEED 257
#define T_IN 2048
#define C_CH 64
#define CH_TILE 4
#define CG (C_CH / CH_TILE)   // 16 channel groups

// ---------------------------------------------------------------------------
// K1: partial masked DFT.
// block = (b, cg, tc); 256 threads = bins k=0..255.
// Computes P[b][cg][tc][ci][k] = sum_{t in chunk, t<L} x[b][c][t] e^{-2pi i k t / L}
// Rotation advance shared across CH_TILE channels; 4-t unroll breaks the chain.
// ---------------------------------------------------------------------------
template<int CHUNK>
__global__ __launch_bounds__(256) void dft_partial_kernel(
    const float* __restrict__ x, const int* __restrict__ length,
    float* __restrict__ P)
{
    constexpr int TC = T_IN / CHUNK;
    const int blk = blockIdx.x;
    const int tc  = blk % TC;
    const int cg  = (blk / TC) % CG;
    const int b   = blk / (TC * CG);
    const int tid = threadIdx.x;
    const int L   = length[b];
    const int t0  = tc * CHUNK;

    float ar[CH_TILE] = {0.f, 0.f, 0.f, 0.f};
    float ai[CH_TILE] = {0.f, 0.f, 0.f, 0.f};

    float* Pb = P + ((((size_t)b * CG + cg) * TC + tc) * CH_TILE) * 512;

    if (L >= OUT_LEN && t0 < L) {
        __shared__ float xs[CH_TILE][CHUNK];
        const float* __restrict__ xbase = x + ((size_t)b * C_CH + cg * CH_TILE) * T_IN;
        for (int idx = tid; idx < CH_TILE * CHUNK; idx += 256) {
            const int ci = idx / CHUNK;
            const int t  = idx % CHUNK;
            const int tt = t0 + t;
            xs[ci][t] = (tt < L) ? xbase[ci * T_IN + tt] : 0.0f;
        }
        __syncthreads();

        const float twoPi = 6.28318530717958647692f;
        const float fL = (float)L;
        const int k = tid;

        // z0 = e^{-2pi i k t0 / L}, exact integer phase reduction
        const int m0 = (int)(((long long)k * (long long)t0) % (long long)L);
        float zi0, zr0;
        sincosf(-twoPi * (float)m0 / fL, &zi0, &zr0);
        float zr = zr0, zi = zi0;

        // step rotators w, w^2, w^3, w^4
        float s1, c1;
        sincosf(-twoPi * (float)k / fL, &s1, &c1);
        const float c2 = c1 * c1 - s1 * s1, s2 = 2.f * c1 * s1;
        const float c3 = c2 * c1 - s2 * s1, s3 = c2 * s1 + s2 * c1;
        const float c4 = c2 * c2 - s2 * s2, s4 = 2.f * c2 * s2;

        #pragma unroll 2
        for (int tq = 0; tq < CHUNK / 4; ++tq) {
            // off-chain rotations for t+1, t+2, t+3
            const float z1r = zr * c1 - zi * s1, z1i = zr * s1 + zi * c1;
            const float z2r = zr * c2 - zi * s2, z2i = zr * s2 + zi * c2;
            const float z3r = zr * c3 - zi * s3, z3i = zr * s3 + zi * c3;
            #pragma unroll
            for (int ci = 0; ci < CH_TILE; ++ci) {
                const float4 v = ((const float4*)xs[ci])[tq];   // broadcast b128
                ar[ci] = fmaf(v.x, zr,  ar[ci]);
                ai[ci] = fmaf(v.x, zi,  ai[ci]);
                ar[ci] = fmaf(v.y, z1r, ar[ci]);
                ai[ci] = fmaf(v.y, z1i, ai[ci]);
                ar[ci] = fmaf(v.z, z2r, ar[ci]);
                ai[ci] = fmaf(v.z, z2i, ai[ci]);
                ar[ci] = fmaf(v.w, z3r, ar[ci]);
                ai[ci] = fmaf(v.w, z3i, ai[ci]);
            }
            const float nzr = zr * c4 - zi * s4;
            const float nzi = zr * s4 + zi * c4;
            zr = nzr; zi = nzi;
        }
    }

    // always write (zeros when inactive) — ws is poisoned, K2 always sums TC parts
    #pragma unroll
    for (int ci = 0; ci < CH_TILE; ++ci) {
        float2* dst = (float2*)(Pb + ci * 512);
        dst[tid] = make_float2(ar[ci], ai[ci]);
    }
}

// ---------------------------------------------------------------------------
// K2: combine partials, Nyquist bin, inverse rfft (n=512), short-copy branch.
// block = (b, c); 256 threads.
// ---------------------------------------------------------------------------
template<int TC>
__global__ __launch_bounds__(256) void combine_inverse_kernel(
    const float* __restrict__ x, const int* __restrict__ length,
    const float* __restrict__ P, float* __restrict__ out)
{
    const int bc  = blockIdx.x;
    const int b   = bc >> 6;
    const int c   = bc & 63;
    const int tid = threadIdx.x;
    const int L   = length[b];

    const float* __restrict__ xrow = x + (size_t)bc * T_IN;
    float* __restrict__ orow = out + (size_t)bc * OUT_LEN;

    if (L < OUT_LEN) {
        for (int t = tid; t < OUT_LEN; t += 256)
            orow[t] = (t < L) ? xrow[t] : 0.0f;
        return;
    }

    __shared__ float2 X[NEED];
    __shared__ float red[256];

    // combine TC partials for bin k = tid
    {
        const int cg = c >> 2, ci = c & 3;
        float xr = 0.f, xi = 0.f;
        #pragma unroll
        for (int tc = 0; tc < TC; ++tc) {
            const float2* src =
                (const float2*)(P + ((((size_t)b * CG + cg) * TC + tc) * CH_TILE + ci) * 512);
            const float2 v = src[tid];
            xr += v.x; xi += v.y;
        }
        X[tid] = make_float2(xr, xi);
    }

    const float twoPi = 6.28318530717958647692f;
    const float fL = (float)L;

    // Nyquist bin k=256 (only Re enters irfft), exact integer phase reduction
    {
        float part = 0.0f;
        for (int t = tid; t < L; t += 256) {
            const int m = (256 * t) % L;
            part = fmaf(xrow[t], cosf(-twoPi * (float)m / fL), part);
        }
        red[tid] = part;
    }
    __syncthreads();
    #pragma unroll
    for (int sft = 128; sft > 0; sft >>= 1) {
        if (tid < sft) red[tid] += red[tid + sft];
        __syncthreads();
    }
    if (tid == 0) X[256] = make_float2(red[0], 0.0f);
    __syncthreads();

    // inverse rfft, norm=backward (1/512), 4-way chain-broken rotation
    {
        const int t = tid;                 // covers outputs t and t+256
        float s1, c1;
        sincosf(twoPi * (float)t / 512.0f, &s1, &c1);   // w = e^{+2pi i t/512}
        const float c2 = c1 * c1 - s1 * s1, s2 = 2.f * c1 * s1;
        const float c3 = c2 * c1 - s2 * s1, s3 = c2 * s1 + s2 * c1;
        const float c4 = c2 * c2 - s2 * s2, s4 = 2.f * c2 * s2;

        float zr = c1, zi = s1;            // z = w^k at k=1
        float accE = 0.0f, accO = 0.0f;

        for (int k = 1; k <= 249; k += 4) {
            const float z1r = zr * c1 - zi * s1, z1i = zr * s1 + zi * c1;
            const float z2r = zr * c2 - zi * s2, z2i = zr * s2 + zi * c2;
            const float z3r = zr * c3 - zi * s3, z3i = zr * s3 + zi * c3;
            const float2 X0 = X[k], X1 = X[k + 1], X2 = X[k + 2], X3 = X[k + 3];
            accO = fmaf(X0.x, zr,  fmaf(-X0.y, zi,  accO));   // k   odd
            accE = fmaf(X1.x, z1r, fmaf(-X1.y, z1i, accE));   // k+1 even
            accO = fmaf(X2.x, z2r, fmaf(-X2.y, z2i, accO));   // k+2 odd
            accE = fmaf(X3.x, z3r, fmaf(-X3.y, z3i, accE));   // k+3 even
            const float nzr = zr * c4 - zi * s4;
            const float nzi = zr * s4 + zi * c4;
            zr = nzr; zi = nzi;
        }
        // tail k = 253 (odd), 254 (even), 255 (odd); z = w^253 here
        {
            const float z1r = zr * c1 - zi * s1, z1i = zr * s1 + zi * c1;
            const float z2r = zr * c2 - zi * s2, z2i = zr * s2 + zi * c2;
            const float2 X0 = X[253], X1 = X[254], X2 = X[255];
            accO = fmaf(X0.x, zr,  fmaf(-X0.y, zi,  accO));
            accE = fmaf(X1.x, z1r, fmaf(-X1.y, z1i, accE));
            accO = fmaf(X2.x, z2r, fmaf(-X2.y, z2i, accO));
        }

        const float base = X[0].x + ((t & 1) ? -X[256].x : X[256].x);
        const float invN = 1.0f / 512.0f;
        orow[t]       = (base + 2.0f * (accE + accO)) * invN;
        orow[t + 256] = (base + 2.0f * (accE - accO)) * invN;
    }
}

// ---------------------------------------------------------------------------
// Monolithic fallback (round-1 kernel) — used only if d_ws is too small.
// ---------------------------------------------------------------------------
__global__ __launch_bounds__(256) void spectral_pool_mono(
    const float* __restrict__ x, const int* __restrict__ length,
    float* __restrict__ out)
{
    const int bc  = blockIdx.x;
    const int b   = bc >> 6;
    const int tid = threadIdx.x;
    const int L   = length[b];

    const float* __restrict__ xrow = x + (size_t)bc * T_IN;
    float* __restrict__ orow = out + (size_t)bc * OUT_LEN;

    if (L < OUT_LEN) {
        for (int t = tid; t < OUT_LEN; t += 256)
            orow[t] = (t < L) ? xrow[t] : 0.0f;
        return;
    }

    __shared__ float xs[T_IN];
    __shared__ float Xr[NEED];
    __shared__ float Xi[NEED];
    __shared__ float red[256];

    {
        const float4* __restrict__ src = (const float4*)xrow;
        float4* dst = (float4*)xs;
        #pragma unroll
        for (int i = 0; i < T_IN / 4 / 256; ++i)
            dst[tid + i * 256] = src[tid + i * 256];
    }
    __syncthreads();

    const float twoPi = 6.28318530717958647692f;
    const float fL = (float)L;

    {
        const int k = tid;
        float s, co;
        sincosf(-twoPi * (float)k / fL, &s, &co);
        float zr = 1.0f, zi = 0.0f;
        float arr = 0.0f, aii = 0.0f;
        for (int t = 0; t < L; ++t) {
            const float xv = xs[t];
            arr = fmaf(xv, zr, arr);
            aii = fmaf(xv, zi, aii);
            const float nzr = fmaf(zr, co, -zi * s);
            const float nzi = fmaf(zr, s,   zi * co);
            zr = nzr; zi = nzi;
        }
        Xr[k] = arr;
        Xi[k] = aii;
    }

    {
        float part = 0.0f;
        for (int t = tid; t < L; t += 256) {
            const int m = (256 * t) % L;
            part = fmaf(xs[t], cosf(-twoPi * (float)m / fL), part);
        }
        red[tid] = part;
    }
    __syncthreads();
    #pragma unroll
    for (int sft = 128; sft > 0; sft >>= 1) {
        if (tid < sft) red[tid] += red[tid + sft];
        __syncthreads();
    }
    if (tid == 0) { Xr[256] = red[0]; Xi[256] = 0.0f; }
    __syncthreads();

    {
        const int t = tid;
        float s, co;
        sincosf(twoPi * (float)t / 512.0f, &s, &co);
        float zr = co, zi = s;
        float accE = 0.0f, accO = 0.0f;
        #pragma unroll 2
        for (int k = 1; k < 256; ++k) {
            const float re = fmaf(Xr[k], zr, -Xi[k] * zi);
            if (k & 1) accO += re; else accE += re;
            const float nzr = fmaf(zr, co, -zi * s);
            const float nzi = fmaf(zr, s,   zi * co);
            zr = nzr; zi = nzi;
        }
        const float base = Xr[0] + ((t & 1) ? -Xr[256] : Xr[256]);
        const float invN = 1.0f / 512.0f;
        orow[t]       = (base + 2.0f * (accE + accO)) * invN;
        orow[t + 256] = (base + 2.0f * (accE - accO)) * invN;
    }
}

// ---------------------------------------------------------------------------
template<int CHUNK>
static void launch_pipeline(const float* x, const int* length, float* P,
                            float* out, int B, hipStream_t stream)
{
    constexpr int TC = T_IN / CHUNK;
    hipLaunchKernelGGL((dft_partial_kernel<CHUNK>), dim3(B * CG * TC), dim3(256), 0, stream,
                       x, length, P);
    hipLaunchKernelGGL((combine_inverse_kernel<TC>), dim3(B * C_CH), dim3(256), 0, stream,
                       x, length, P, out);
}

extern "C" void kernel_launch(void* const* d_in, const int* in_sizes, int n_in,
                              void* d_out, int out_size, void* d_ws, size_t ws_size,
                              hipStream_t stream) {
    const float* x      = (const float*)d_in[0];
    const int*   length = (const int*)d_in[1];
    float*       out    = (float*)d_out;
    float*       P      = (float*)d_ws;
    const int B = in_sizes[1];

    auto need = [&](int TC) {
        return (size_t)B * CG * TC * CH_TILE * 512 * sizeof(float);
    };

    if (ws_size >= need(8)) {
        launch_pipeline<256>(x, length, P, out, B, stream);     // TC=8
    } else if (ws_size >= need(4)) {
        launch_pipeline<512>(x, length, P, out, B, stream);     // TC=4
    } else if (ws_size >= need(2)) {
        launch_pipeline<1024>(x, length, P, out, B, stream);    // TC=2
    } else if (ws_size >= need(1)) {
        launch_pipeline<2048>(x, length, P, out, B, stream);    // TC=1
    } else {
        hipLaunchKernelGGL(spectral_pool_mono, dim3(B * C_CH), dim3(256), 0, stream,
                           x, length, out);
    }
}

// Round 3
// 29.618 us; speedup vs baseline: 2.1463x; 1.9340x over previous
//
#include <hip/hip_runtime.h>
#include <math.h>

#define OUT_LEN 512
#define T_IN    2048
#define C_CH    64
#define BN      32                 // tau columns per block
#define BK      64                 // t (K) chunk per stage
#define NTT     (OUT_LEN / BN)     // 16 tau-tiles

typedef __attribute__((ext_vector_type(8))) short bf16x8;
typedef __attribute__((ext_vector_type(4))) float f32x4;

static __device__ __forceinline__ short f2bf(float f) {
    unsigned int u = __float_as_uint(f);
    unsigned int r = (u + 0x7FFFu + ((u >> 16) & 1u)) >> 16;   // RNE
    return (short)r;
}

// ---------------------------------------------------------------------------
// GEMM: out_partial[h][b][c][tau] = sum over t-chunks of parity h of
//       x[b][c][t] * M_L[t][tau],  M built on the fly in LDS (bf16).
// bid = tt*(2B) + b*2 + h  (tau-tile-major => same-batch blocks share XCD)
// ---------------------------------------------------------------------------
__global__ __launch_bounds__(256) void spectral_gemm(
    const float* __restrict__ x, const int* __restrict__ length,
    float* __restrict__ P, int B)
{
    const int bid = blockIdx.x;
    const int h   = bid & 1;
    const int rem = bid >> 1;
    const int b   = rem % B;
    const int tt  = rem / B;
    const int tid = threadIdx.x;
    const int L   = length[b];
    if (L < OUT_LEN) return;                    // combine handles copy branch

    const int tau0 = tt * BN;
    const float* __restrict__ xb = x + (size_t)b * C_CH * T_IN;

    __shared__ short A_lds[4][2][64][8];        // [w][ksub][lane][i] bf16
    __shared__ short B_lds[2][2][64][8];        // [j][ksub][lane][i] bf16

    // ---- staging-role constants (x -> A fragments) ----
    const int fq  = tid & 15;                   // float4 index along t
    const int cb  = tid >> 4;                   // base channel 0..15
    const int ksA = fq >> 3;
    const int gA  = (fq >> 1) & 3;
    const int i0A = (fq & 1) * 4;

    // ---- build-role constants (M -> B fragments) ----
    const int tau_l = tid & 31;
    const int tauv  = tau0 + tau_l;             // global tau 0..511
    const int tb8   = (tid >> 5) << 3;          // 0,8,...,56
    const int jB    = tau_l >> 4;
    const int gB    = (tb8 >> 3) & 3;
    const int ksubB = tb8 >> 5;
    const int laneB = (tau_l & 15) + (gB << 4);

    // ---- integer phase state: n = 512*t - tau*L reduced to (-256L, 256L],
    //      m = n mod 2L reduced to (-L, L] ----
    const int L2   = L << 1;
    const int L256 = L << 8;
    const int L512 = L << 9;
    const float inv2Lf   = 1.0f / (float)L2;
    const float inv1024L = 1.0f / (float)(L << 10);

    int n0 = 512 * (h * BK + tb8) - tauv * L;
    if (n0 <= -L256) n0 += L512;                // single add suffices
    int q0 = (int)rintf((float)n0 * inv2Lf);
    int m0 = n0 - q0 * L2;
    if (m0 <= -L) m0 += L2;
    if (m0 >   L) m0 -= L2;
    // chunk advance deltas (t += 128)
    const int qc  = (int)rintf(65536.0f * inv2Lf);
    const int dmc = 65536 - qc * L2;            // in [-L, L]

    const int nc = (L + BK - 1) / BK;

    f32x4 acc0 = {0.f, 0.f, 0.f, 0.f};
    f32x4 acc1 = {0.f, 0.f, 0.f, 0.f};

    const int lane = tid & 63;
    const int wid  = tid >> 6;

    // ---- prologue: prefetch first chunk's x ----
    float4 pf[4];
    {
        const int t0 = h * BK;
        #pragma unroll
        for (int r = 0; r < 4; ++r)
            pf[r] = *(const float4*)(xb + (size_t)(cb + 16 * r) * T_IN + t0 + fq * 4);
    }

    for (int s = h; s < nc; s += 2) {
        const int t0 = s * BK;
        __syncthreads();                        // LDS free (prev MFMA done)

        // ---- write A fragments (bf16, masked t>=L) ----
        {
            const int tb = t0 + fq * 4;
            #pragma unroll
            for (int r = 0; r < 4; ++r) {
                float4 v = pf[r];
                v.x = (tb + 0 < L) ? v.x : 0.0f;
                v.y = (tb + 1 < L) ? v.y : 0.0f;
                v.z = (tb + 2 < L) ? v.z : 0.0f;
                v.w = (tb + 3 < L) ? v.w : 0.0f;
                union { short s[4]; long long ll; } w;
                w.s[0] = f2bf(v.x); w.s[1] = f2bf(v.y);
                w.s[2] = f2bf(v.z); w.s[3] = f2bf(v.w);
                *(long long*)&A_lds[r][ksA][cb + (gA << 4)][i0A] = w.ll;
            }
        }

        // ---- prefetch next chunk (latency hidden under M-build) ----
        if (s + 2 < nc) {
            const int tn = t0 + 2 * BK;
            #pragma unroll
            for (int r = 0; r < 4; ++r)
                pf[r] = *(const float4*)(xb + (size_t)(cb + 16 * r) * T_IN + tn + fq * 4);
        }

        // ---- build M chunk: 8 entries per thread, one b128 write ----
        {
            int nd = n0, md = m0;
            union { short s[8]; int4 v; } pk;
            #pragma unroll
            for (int d = 0; d < 8; ++d) {
                const float u2 = (float)nd * inv1024L;       // half-angle, revolutions
                float sh = __builtin_amdgcn_sinf(u2);
                const float ch = __builtin_amdgcn_cosf(u2);
                const float u2q = u2 * u2;
                const float poly = u2 * fmaf(u2q, -41.341702f, 6.2831853072f);
                sh = (fabsf(u2) < 2.44140625e-4f) ? poly : sh;
                const float rev = (float)md * inv2Lf;        // in (-0.5, 0.5]
                const float sv = __builtin_amdgcn_sinf(rev);
                float Mv = sv * ch * __builtin_amdgcn_rcpf(sh) * 0.001953125f;
                Mv = (nd == 0) ? 1.0f : Mv;                  // singular: exact copy weight
                Mv = (t0 + tb8 + d < L) ? Mv : 0.0f;         // tail mask (also kills inf/NaN)
                pk.s[d] = f2bf(Mv);
                nd += 512; if (nd > L256) nd -= L512;
                md += 512; if (md > L)    md -= L2;
            }
            *(int4*)&B_lds[jB][ksubB][laneB][0] = pk.v;
        }

        // ---- advance chunk state ----
        n0 += 65536; if (n0 > L256) n0 -= L512;
        m0 += dmc;   if (m0 > L)    m0 -= L2;
        if (m0 <= -L) m0 += L2;

        __syncthreads();

        // ---- MFMA: [16x32] per wave over both 16-tau tiles ----
        {
            const bf16x8 a0  = *(const bf16x8*)&A_lds[wid][0][lane][0];
            const bf16x8 a1  = *(const bf16x8*)&A_lds[wid][1][lane][0];
            const bf16x8 b00 = *(const bf16x8*)&B_lds[0][0][lane][0];
            const bf16x8 b01 = *(const bf16x8*)&B_lds[0][1][lane][0];
            const bf16x8 b10 = *(const bf16x8*)&B_lds[1][0][lane][0];
            const bf16x8 b11 = *(const bf16x8*)&B_lds[1][1][lane][0];
            acc0 = __builtin_amdgcn_mfma_f32_16x16x32_bf16(a0, b00, acc0, 0, 0, 0);
            acc0 = __builtin_amdgcn_mfma_f32_16x16x32_bf16(a1, b01, acc0, 0, 0, 0);
            acc1 = __builtin_amdgcn_mfma_f32_16x16x32_bf16(a0, b10, acc1, 0, 0, 0);
            acc1 = __builtin_amdgcn_mfma_f32_16x16x32_bf16(a1, b11, acc1, 0, 0, 0);
        }
    }

    // ---- epilogue: write partial tile ----
    {
        float* Pb = P + (size_t)h * ((size_t)B * C_CH * OUT_LEN)
                      + ((size_t)b * C_CH + wid * 16 + (lane >> 4) * 4) * OUT_LEN
                      + tau0 + (lane & 15);
        #pragma unroll
        for (int r = 0; r < 4; ++r) {
            Pb[(size_t)r * OUT_LEN + 0]  = acc0[r];
            Pb[(size_t)r * OUT_LEN + 16] = acc1[r];
        }
    }
}

// ---------------------------------------------------------------------------
// Combine: out = P0 + P1 (L>=512) or masked copy of x (L<512).
// One float4 per thread.
// ---------------------------------------------------------------------------
__global__ __launch_bounds__(256) void spectral_combine(
    const float* __restrict__ x, const int* __restrict__ length,
    const float* __restrict__ P, float* __restrict__ out, int B)
{
    const int idx = blockIdx.x * 256 + threadIdx.x;       // float4 index
    const int total = B * C_CH * (OUT_LEN / 4);
    if (idx >= total) return;
    const int t4 = idx & (OUT_LEN / 4 - 1);
    const int c  = (idx >> 7) & (C_CH - 1);
    const int b  = idx >> 13;
    const int L  = length[b];

    float4 o;
    if (L < OUT_LEN) {
        const int t = t4 * 4;
        float4 v = *(const float4*)(x + ((size_t)b * C_CH + c) * T_IN + t);
        o.x = (t + 0 < L) ? v.x : 0.0f;
        o.y = (t + 1 < L) ? v.y : 0.0f;
        o.z = (t + 2 < L) ? v.z : 0.0f;
        o.w = (t + 3 < L) ? v.w : 0.0f;
    } else {
        const size_t half = (size_t)B * C_CH * OUT_LEN / 4;   // in float4 units
        const float4 p0 = ((const float4*)P)[idx];
        const float4 p1 = ((const float4*)P)[half + idx];
        o.x = p0.x + p1.x; o.y = p0.y + p1.y;
        o.z = p0.z + p1.z; o.w = p0.w + p1.w;
    }
    ((float4*)out)[idx] = o;
}

// ---------------------------------------------------------------------------
// Monolithic fallback (round-1, known-correct) if ws too small.
// ---------------------------------------------------------------------------
__global__ __launch_bounds__(256) void spectral_pool_mono(
    const float* __restrict__ x, const int* __restrict__ length,
    float* __restrict__ out)
{
    const int bc  = blockIdx.x;
    const int b   = bc >> 6;
    const int tid = threadIdx.x;
    const int L   = length[b];

    const float* __restrict__ xrow = x + (size_t)bc * T_IN;
    float* __restrict__ orow = out + (size_t)bc * OUT_LEN;

    if (L < OUT_LEN) {
        for (int t = tid; t < OUT_LEN; t += 256)
            orow[t] = (t < L) ? xrow[t] : 0.0f;
        return;
    }

    __shared__ float xs[T_IN];
    __shared__ float Xr[257];
    __shared__ float Xi[257];
    __shared__ float red[256];

    {
        const float4* __restrict__ src = (const float4*)xrow;
        float4* dst = (float4*)xs;
        #pragma unroll
        for (int i = 0; i < T_IN / 4 / 256; ++i)
            dst[tid + i * 256] = src[tid + i * 256];
    }
    __syncthreads();

    const float twoPi = 6.28318530717958647692f;
    const float fL = (float)L;

    {
        const int k = tid;
        float s, co;
        sincosf(-twoPi * (float)k / fL, &s, &co);
        float zr = 1.0f, zi = 0.0f;
        float arr = 0.0f, aii = 0.0f;
        for (int t = 0; t < L; ++t) {
            const float xv = xs[t];
            arr = fmaf(xv, zr, arr);
            aii = fmaf(xv, zi, aii);
            const float nzr = fmaf(zr, co, -zi * s);
            const float nzi = fmaf(zr, s,   zi * co);
            zr = nzr; zi = nzi;
        }
        Xr[k] = arr;
        Xi[k] = aii;
    }
    {
        float part = 0.0f;
        for (int t = tid; t < L; t += 256) {
            const int m = (256 * t) % L;
            part = fmaf(xs[t], cosf(-twoPi * (float)m / fL), part);
        }
        red[tid] = part;
    }
    __syncthreads();
    #pragma unroll
    for (int sft = 128; sft > 0; sft >>= 1) {
        if (tid < sft) red[tid] += red[tid + sft];
        __syncthreads();
    }
    if (tid == 0) { Xr[256] = red[0]; Xi[256] = 0.0f; }
    __syncthreads();
    {
        const int t = tid;
        float s, co;
        sincosf(twoPi * (float)t / 512.0f, &s, &co);
        float zr = co, zi = s;
        float accE = 0.0f, accO = 0.0f;
        #pragma unroll 2
        for (int k = 1; k < 256; ++k) {
            const float re = fmaf(Xr[k], zr, -Xi[k] * zi);
            if (k & 1) accO += re; else accE += re;
            const float nzr = fmaf(zr, co, -zi * s);
            const float nzi = fmaf(zr, s,   zi * co);
            zr = nzr; zi = nzi;
        }
        const float base = Xr[0] + ((t & 1) ? -Xr[256] : Xr[256]);
        const float invN = 1.0f / 512.0f;
        orow[t]       = (base + 2.0f * (accE + accO)) * invN;
        orow[t + 256] = (base + 2.0f * (accE - accO)) * invN;
    }
}

extern "C" void kernel_launch(void* const* d_in, const int* in_sizes, int n_in,
                              void* d_out, int out_size, void* d_ws, size_t ws_size,
                              hipStream_t stream) {
    const float* x      = (const float*)d_in[0];
    const int*   length = (const int*)d_in[1];
    float*       out    = (float*)d_out;
    float*       P      = (float*)d_ws;
    const int B = in_sizes[1];

    const size_t needP = 2ull * B * C_CH * OUT_LEN * sizeof(float);
    if (ws_size >= needP) {
        const int gemm_blocks = NTT * B * 2;                  // 512 for B=16
        hipLaunchKernelGGL(spectral_gemm, dim3(gemm_blocks), dim3(256), 0, stream,
                           x, length, P, B);
        const int cmb_threads = B * C_CH * (OUT_LEN / 4);
        hipLaunchKernelGGL(spectral_combine, dim3((cmb_threads + 255) / 256), dim3(256),
                           0, stream, x, length, P, out, B);
    } else {
        hipLaunchKernelGGL(spectral_pool_mono, dim3(B * C_CH), dim3(256), 0, stream,
                           x, length, out);
    }
}

// Round 4
// 24.737 us; speedup vs baseline: 2.5698x; 1.1973x over previous
//
#include <hip/hip_runtime.h>
#include <math.h>

#define OUT_LEN 512
#define T_IN    2048
#define C_CH    64
#define BN      32
#define NTT     (OUT_LEN / BN)   // 16 tau-tiles
#define KSPLIT  4

typedef __attribute__((ext_vector_type(8))) short bf16x8;
typedef __attribute__((ext_vector_type(4))) float f32x4;

static __device__ __forceinline__ short f2bf(float f) {
    unsigned int u = __float_as_uint(f);
    unsigned int r = (u + 0x7FFFu + ((u >> 16) & 1u)) >> 16;   // RNE
    return (short)r;
}

// ---------------------------------------------------------------------------
// K0: convert x (f32) -> xbf (bf16), 8 elements/thread.
// ---------------------------------------------------------------------------
__global__ __launch_bounds__(256) void convert_kernel(
    const float* __restrict__ x, unsigned short* __restrict__ xbf, int total8)
{
    const int i = blockIdx.x * 256 + threadIdx.x;
    if (i >= total8) return;
    const float4 v0 = ((const float4*)x)[2 * i];
    const float4 v1 = ((const float4*)x)[2 * i + 1];
    union { short s[8]; int4 v; } pk;
    pk.s[0] = f2bf(v0.x); pk.s[1] = f2bf(v0.y);
    pk.s[2] = f2bf(v0.z); pk.s[3] = f2bf(v0.w);
    pk.s[4] = f2bf(v1.x); pk.s[5] = f2bf(v1.y);
    pk.s[6] = f2bf(v1.z); pk.s[7] = f2bf(v1.w);
    ((int4*)xbf)[i] = pk.v;
}

// ---------------------------------------------------------------------------
// K1: GEMM with on-the-fly M. M_L[t][tau] = sin(pi*n/L)*cot(pi*n/(512L))/512,
// n = 512t - tau*L (periodic mod 512L; singular n==0 -> 1; t>=L -> 0).
// sin from per-block LDS table (index |n mod 2L|, only 2 values per tau-parity
// => broadcast reads); cot = 1/(pi*u) + u*poly(u^2), u = n/(512L) in (-.5,.5].
// Grid: bid = (b*NTT + tt)*4 + h; block = 256 thr = 4 waves; chunk = 64 t.
// ---------------------------------------------------------------------------
__global__ __launch_bounds__(256) void spectral_gemm(
    const unsigned short* __restrict__ xbf, const int* __restrict__ length,
    float* __restrict__ P, int B)
{
    const int bid = blockIdx.x;
    const int h   = bid & 3;
    const int rem = bid >> 2;
    const int tt  = rem % NTT;
    const int b   = rem / NTT;
    const int tid = threadIdx.x;
    const int L   = length[b];
    if (L < OUT_LEN) return;

    const int tau0 = tt * BN;

    __shared__ short A_lds[4][2][64][8];
    __shared__ short B_lds[2][2][64][8];
    __shared__ float tab[T_IN + 1];

    // sv table: tab[i] = sin(pi*i/L)/512, i in [0, L]
    {
        const float stp = 0.5f / (float)L;              // revolutions per index
        for (int i = tid; i <= L; i += 256)
            tab[i] = __builtin_amdgcn_sinf(stp * (float)i) * 0.001953125f;
    }

    // ---- staging role: wave wid stages region wid, lane -> fragment ----
    const int lane = tid & 63;
    const int wid  = tid >> 6;
    const unsigned short* gsrcBase =
        xbf + ((size_t)(b * C_CH + wid * 16 + (lane & 15))) * T_IN + ((lane >> 4) * 8);

    // ---- build role ----
    const int tau_l = tid & 31;
    const int tauv  = tau0 + tau_l;
    const int tb8   = (tid >> 5) << 3;                  // 0,8,...,56
    const int jB    = tau_l >> 4;
    const int gB    = (tb8 >> 3) & 3;
    const int ksubB = tb8 >> 5;
    const int laneB = (tau_l & 15) + (gB << 4);

    const int L2v  = L << 1;
    const int L256 = L << 8;
    const int L512 = L << 9;
    const float inv2Lf    = 1.0f / (float)L2v;
    const float inv512L   = 1.0f / (float)L512;
    const float piInv512L = 3.14159265358979f * inv512L;

    // initial n0 = 512*t_first - tau*L, fully reduced to (-256L, 256L]
    int n0 = 512 * (h * 64 + tb8) - tauv * L;
    {
        const int q = (int)rintf((float)n0 * inv512L);
        n0 -= q * L512;
        if (n0 <= -L256) n0 += L512;
        if (n0 >   L256) n0 -= L512;
    }
    int m0;                                             // n0 mod 2L in (-L, L]
    {
        const int q0 = (int)rintf((float)n0 * inv2Lf);
        m0 = n0 - q0 * L2v;
        if (m0 <= -L) m0 += L2v;
        if (m0 >   L) m0 -= L2v;
    }
    int dmc;                                            // 131072 mod 2L in [0, 2L)
    {
        const int qc = (int)rintf(131072.0f * inv2Lf);
        dmc = 131072 - qc * L2v;
        if (dmc < 0)     dmc += L2v;
        if (dmc >= L2v)  dmc -= L2v;
    }

    const int nc = (L + 63) >> 6;

    f32x4 acc0 = {0.f, 0.f, 0.f, 0.f};
    f32x4 acc1 = {0.f, 0.f, 0.f, 0.f};

    // prologue prefetch (bf16, no masking needed: M masks t>=L)
    int4 pf0, pf1;
    {
        const unsigned short* g = gsrcBase + h * 64;
        pf0 = *(const int4*)(g);
        pf1 = *(const int4*)(g + 32);
    }

    for (int s = h; s < nc; s += KSPLIT) {
        const int t0 = s << 6;
        __syncthreads();                                // A/B free, tab ready

        // write A fragments (2 x ds_write_b128 per thread)
        *(int4*)&A_lds[wid][0][lane][0] = pf0;
        *(int4*)&A_lds[wid][1][lane][0] = pf1;

        // prefetch next chunk (hidden under M-build)
        if (s + KSPLIT < nc) {
            const unsigned short* g = gsrcBase + (t0 + KSPLIT * 64);
            pf0 = *(const int4*)(g);
            pf1 = *(const int4*)(g + 32);
        }

        // ---- build M chunk: 8 entries/thread ----
        {
            int nd = n0, md = m0;
            union { short s[8]; int4 v; } pk;
            const int tbase = t0 + tb8;
            #pragma unroll
            for (int d = 0; d < 8; ++d) {
                const float nf = (float)nd;
                const float u  = nf * inv512L;          // (-0.5, 0.5]
                const float w  = nf * piInv512L;        // pi*u
                const float ru = __builtin_amdgcn_rcpf(w);
                const float u2 = u * u;
                const float p  = fmaf(u2, fmaf(u2, -0.64766070f, -0.68902837f),
                                      -1.04719755f);
                const float cotv = fmaf(u, p, ru);      // cot(pi*u), err<=0.007
                const int am = (md < 0) ? -md : md;
                float sv = tab[am];                     // sin(pi*am/L)/512 (broadcast)
                sv = (md < 0) ? -sv : sv;
                float Mv = sv * cotv;
                Mv = (nd == 0) ? 1.0f : Mv;             // singular: exact 1
                Mv = (tbase + d < L) ? Mv : 0.0f;       // tail mask
                pk.s[d] = f2bf(Mv);
                nd += 512; if (nd > L256) nd -= L512;
                md += 512; if (md > L)    md -= L2v;
            }
            *(int4*)&B_lds[jB][ksubB][laneB][0] = pk.v;
        }

        // advance persistent state (t += 256)
        n0 += 131072; if (n0 > L256) n0 -= L512;
        m0 += dmc;    if (m0 > L)    m0 -= L2v;

        __syncthreads();

        const bf16x8 a0  = *(const bf16x8*)&A_lds[wid][0][lane][0];
        const bf16x8 a1  = *(const bf16x8*)&A_lds[wid][1][lane][0];
        const bf16x8 b00 = *(const bf16x8*)&B_lds[0][0][lane][0];
        const bf16x8 b01 = *(const bf16x8*)&B_lds[0][1][lane][0];
        const bf16x8 b10 = *(const bf16x8*)&B_lds[1][0][lane][0];
        const bf16x8 b11 = *(const bf16x8*)&B_lds[1][1][lane][0];
        acc0 = __builtin_amdgcn_mfma_f32_16x16x32_bf16(a0, b00, acc0, 0, 0, 0);
        acc0 = __builtin_amdgcn_mfma_f32_16x16x32_bf16(a1, b01, acc0, 0, 0, 0);
        acc1 = __builtin_amdgcn_mfma_f32_16x16x32_bf16(a0, b10, acc1, 0, 0, 0);
        acc1 = __builtin_amdgcn_mfma_f32_16x16x32_bf16(a1, b11, acc1, 0, 0, 0);
    }

    // epilogue: write this h's partial
    {
        float* Pb = P + (size_t)h * ((size_t)B * C_CH * OUT_LEN)
                      + ((size_t)b * C_CH + wid * 16 + ((lane >> 4) << 2)) * OUT_LEN
                      + tau0 + (lane & 15);
        #pragma unroll
        for (int r = 0; r < 4; ++r) {
            Pb[(size_t)r * OUT_LEN]      = acc0[r];
            Pb[(size_t)r * OUT_LEN + 16] = acc1[r];
        }
    }
}

// ---------------------------------------------------------------------------
// K2: out = sum of 4 partials (L>=512) or masked copy (L<512).
// ---------------------------------------------------------------------------
__global__ __launch_bounds__(256) void spectral_combine(
    const float* __restrict__ x, const int* __restrict__ length,
    const float* __restrict__ P, float* __restrict__ out, int B)
{
    const int idx = blockIdx.x * 256 + threadIdx.x;     // float4 index
    const int total = B * C_CH * (OUT_LEN / 4);
    if (idx >= total) return;
    const int t4 = idx & (OUT_LEN / 4 - 1);
    const int c  = (idx >> 7) & (C_CH - 1);
    const int b  = idx >> 13;
    const int L  = length[b];

    float4 o;
    if (L < OUT_LEN) {
        const int t = t4 * 4;
        float4 v = *(const float4*)(x + ((size_t)b * C_CH + c) * T_IN + t);
        o.x = (t + 0 < L) ? v.x : 0.0f;
        o.y = (t + 1 < L) ? v.y : 0.0f;
        o.z = (t + 2 < L) ? v.z : 0.0f;
        o.w = (t + 3 < L) ? v.w : 0.0f;
    } else {
        const size_t quarter = (size_t)B * C_CH * (OUT_LEN / 4);  // float4 units
        const float4 p0 = ((const float4*)P)[idx];
        const float4 p1 = ((const float4*)P)[quarter + idx];
        const float4 p2 = ((const float4*)P)[2 * quarter + idx];
        const float4 p3 = ((const float4*)P)[3 * quarter + idx];
        o.x = (p0.x + p1.x) + (p2.x + p3.x);
        o.y = (p0.y + p1.y) + (p2.y + p3.y);
        o.z = (p0.z + p1.z) + (p2.z + p3.z);
        o.w = (p0.w + p1.w) + (p2.w + p3.w);
    }
    ((float4*)out)[idx] = o;
}

// ---------------------------------------------------------------------------
// Monolithic fallback (round-1, known-correct) if ws too small.
// ---------------------------------------------------------------------------
__global__ __launch_bounds__(256) void spectral_pool_mono(
    const float* __restrict__ x, const int* __restrict__ length,
    float* __restrict__ out)
{
    const int bc  = blockIdx.x;
    const int b   = bc >> 6;
    const int tid = threadIdx.x;
    const int L   = length[b];

    const float* __restrict__ xrow = x + (size_t)bc * T_IN;
    float* __restrict__ orow = out + (size_t)bc * OUT_LEN;

    if (L < OUT_LEN) {
        for (int t = tid; t < OUT_LEN; t += 256)
            orow[t] = (t < L) ? xrow[t] : 0.0f;
        return;
    }

    __shared__ float xs[T_IN];
    __shared__ float Xr[257];
    __shared__ float Xi[257];
    __shared__ float red[256];

    {
        const float4* __restrict__ src = (const float4*)xrow;
        float4* dst = (float4*)xs;
        #pragma unroll
        for (int i = 0; i < T_IN / 4 / 256; ++i)
            dst[tid + i * 256] = src[tid + i * 256];
    }
    __syncthreads();

    const float twoPi = 6.28318530717958647692f;
    const float fL = (float)L;

    {
        const int k = tid;
        float s, co;
        sincosf(-twoPi * (float)k / fL, &s, &co);
        float zr = 1.0f, zi = 0.0f;
        float arr = 0.0f, aii = 0.0f;
        for (int t = 0; t < L; ++t) {
            const float xv = xs[t];
            arr = fmaf(xv, zr, arr);
            aii = fmaf(xv, zi, aii);
            const float nzr = fmaf(zr, co, -zi * s);
            const float nzi = fmaf(zr, s,   zi * co);
            zr = nzr; zi = nzi;
        }
        Xr[k] = arr;
        Xi[k] = aii;
    }
    {
        float part = 0.0f;
        for (int t = tid; t < L; t += 256) {
            const int m = (256 * t) % L;
            part = fmaf(xs[t], cosf(-twoPi * (float)m / fL), part);
        }
        red[tid] = part;
    }
    __syncthreads();
    #pragma unroll
    for (int sft = 128; sft > 0; sft >>= 1) {
        if (tid < sft) red[tid] += red[tid + sft];
        __syncthreads();
    }
    if (tid == 0) { Xr[256] = red[0]; Xi[256] = 0.0f; }
    __syncthreads();
    {
        const int t = tid;
        float s, co;
        sincosf(twoPi * (float)t / 512.0f, &s, &co);
        float zr = co, zi = s;
        float accE = 0.0f, accO = 0.0f;
        #pragma unroll 2
        for (int k = 1; k < 256; ++k) {
            const float re = fmaf(Xr[k], zr, -Xi[k] * zi);
            if (k & 1) accO += re; else accE += re;
            const float nzr = fmaf(zr, co, -zi * s);
            const float nzi = fmaf(zr, s,   zi * co);
            zr = nzr; zi = nzi;
        }
        const float base = Xr[0] + ((t & 1) ? -Xr[256] : Xr[256]);
        const float invN = 1.0f / 512.0f;
        orow[t]       = (base + 2.0f * (accE + accO)) * invN;
        orow[t + 256] = (base + 2.0f * (accE - accO)) * invN;
    }
}

extern "C" void kernel_launch(void* const* d_in, const int* in_sizes, int n_in,
                              void* d_out, int out_size, void* d_ws, size_t ws_size,
                              hipStream_t stream) {
    const float* x      = (const float*)d_in[0];
    const int*   length = (const int*)d_in[1];
    float*       out    = (float*)d_out;
    const int B = in_sizes[1];

    const size_t xbf_bytes = (size_t)B * C_CH * T_IN * 2;              // 4 MB
    const size_t P_bytes   = (size_t)KSPLIT * B * C_CH * OUT_LEN * 4;  // 8 MB

    if (ws_size >= xbf_bytes + P_bytes) {
        unsigned short* xbf = (unsigned short*)d_ws;
        float* P = (float*)((char*)d_ws + xbf_bytes);

        const int total8 = B * C_CH * T_IN / 8;
        hipLaunchKernelGGL(convert_kernel, dim3((total8 + 255) / 256), dim3(256),
                           0, stream, x, xbf, total8);
        hipLaunchKernelGGL(spectral_gemm, dim3(B * NTT * KSPLIT), dim3(256),
                           0, stream, xbf, length, P, B);
        const int cmb = B * C_CH * (OUT_LEN / 4);
        hipLaunchKernelGGL(spectral_combine, dim3((cmb + 255) / 256), dim3(256),
                           0, stream, x, length, P, out, B);
    } else {
        hipLaunchKernelGGL(spectral_pool_mono, dim3(B * C_CH), dim3(256), 0, stream,
                           x, length, out);
    }
}

// Round 5
// 19.898 us; speedup vs baseline: 3.1948x; 1.2432x over previous
//
#include <hip/hip_runtime.h>
#include <math.h>

#define OUT_LEN 512
#define T_IN    2048
#define C_CH    64
#define BN      32
#define NTT     (OUT_LEN / BN)   // 16 tau-tiles
#define KSPLIT  4

typedef __attribute__((ext_vector_type(8))) short bf16x8;
typedef __attribute__((ext_vector_type(4))) float f32x4;

static __device__ __forceinline__ short f2bf(float f) {
    unsigned int u = __float_as_uint(f);
    unsigned int r = (u + 0x7FFFu + ((u >> 16) & 1u)) >> 16;   // RNE
    return (short)r;
}

// ---------------------------------------------------------------------------
// K0: fused prep.
//  - convert x (f32) -> xbf (bf16), 8 elems/thread (all 262144 threads)
//  - init out: zeros for L>=512 batches, masked copy for L<512 (first 131072)
// ---------------------------------------------------------------------------
__global__ __launch_bounds__(256) void prep_kernel(
    const float* __restrict__ x, const int* __restrict__ length,
    unsigned short* __restrict__ xbf, float* __restrict__ out, int B)
{
    const int idx = blockIdx.x * 256 + threadIdx.x;
    const int total8 = B * C_CH * T_IN / 8;
    if (idx < total8) {
        const float4 v0 = ((const float4*)x)[2 * idx];
        const float4 v1 = ((const float4*)x)[2 * idx + 1];
        union { short s[8]; int4 v; } pk;
        pk.s[0] = f2bf(v0.x); pk.s[1] = f2bf(v0.y);
        pk.s[2] = f2bf(v0.z); pk.s[3] = f2bf(v0.w);
        pk.s[4] = f2bf(v1.x); pk.s[5] = f2bf(v1.y);
        pk.s[6] = f2bf(v1.z); pk.s[7] = f2bf(v1.w);
        ((int4*)xbf)[idx] = pk.v;
    }
    const int outq = B * C_CH * (OUT_LEN / 4);
    if (idx < outq) {
        const int b = idx >> 13;                    // 8192 float4 per batch
        const int L = length[b];
        float4 o = {0.f, 0.f, 0.f, 0.f};
        if (L < OUT_LEN) {
            const int t4 = idx & (OUT_LEN / 4 - 1);
            const int c  = (idx >> 7) & (C_CH - 1);
            const int t  = t4 * 4;
            const float4 v = *(const float4*)(x + ((size_t)b * C_CH + c) * T_IN + t);
            o.x = (t + 0 < L) ? v.x : 0.0f;
            o.y = (t + 1 < L) ? v.y : 0.0f;
            o.z = (t + 2 < L) ? v.z : 0.0f;
            o.w = (t + 3 < L) ? v.w : 0.0f;
        }
        ((float4*)out)[idx] = o;
    }
}

// ---------------------------------------------------------------------------
// K1: GEMM with on-the-fly M, atomic accumulation into out.
// M_L[t][tau] = sin(pi*n/L) * cot(pi*n/(512L)) / 512,  n = 512t - tau*L.
// sin(pi*n/L) = (-1)^tau * sin(512*pi*t/L)  ->  per-block table tab[t]
// (tail-masked to 0 for t>=L, /512 folded in); sign folds into cot's argument
// via cot(-x) = -cot(x): use nd' = (-1)^tau * n.
// cot(pi*u) ~ 1/(pi*u) + u*poly(u^2), |u|<=0.5 (err <= 0.007 -> ~1e-5 in M).
// Grid: bid = (b*NTT + tt)*KSPLIT + h; 256 thr = 4 waves; chunk = 64 t.
// ---------------------------------------------------------------------------
__global__ __launch_bounds__(256) void spectral_gemm(
    const unsigned short* __restrict__ xbf, const int* __restrict__ length,
    float* __restrict__ out, int B)
{
    const int bid = blockIdx.x;
    const int h   = bid & (KSPLIT - 1);
    const int rem = bid >> 2;
    const int tt  = rem % NTT;
    const int b   = rem / NTT;
    const int tid = threadIdx.x;
    const int L   = length[b];
    if (L < OUT_LEN) return;                        // prep wrote the copy branch

    const int tau0 = tt * BN;

    __shared__ short A_lds[4][2][64][8];
    __shared__ short B_lds[2][2][64][8];
    __shared__ float tab[T_IN];

    // ---- tab[t] = sin(2*pi*(256t mod L)/L)/512, 0 for t>=L ----
    {
        const float invLf = 1.0f / (float)L;
        int q = (int)(65536.0f * invLf);
        int d256 = 65536 - q * L;                   // 65536 mod L
        if (d256 < 0)  d256 += L;
        if (d256 >= L) d256 -= L;
        const int v = tid << 8;                     // 256*tid
        q = (int)((float)v * invLf);
        int m = v - q * L;
        if (m < 0)  m += L;
        if (m >= L) m -= L;
        for (int i = tid; i < T_IN; i += 256) {
            tab[i] = (i < L)
                ? __builtin_amdgcn_sinf((float)m * invLf) * 0.001953125f : 0.0f;
            m += d256; if (m >= L) m -= L;
        }
    }

    // ---- staging role ----
    const int lane = tid & 63;
    const int wid  = tid >> 6;
    const unsigned short* gsrcBase =
        xbf + ((size_t)(b * C_CH + wid * 16 + (lane & 15))) * T_IN + ((lane >> 4) * 8);

    // ---- build role ----
    const int tau_l = tid & 31;
    const int tauv  = tau0 + tau_l;
    const int tb8   = (tid >> 5) << 3;              // 0,8,...,56
    const int jB    = tau_l >> 4;
    const int gB    = (tb8 >> 3) & 3;
    const int ksubB = tb8 >> 5;
    const int laneB = (tau_l & 15) + (gB << 4);

    const int L256 = L << 8;
    const int L512 = L << 9;
    const float inv512L   = 1.0f / (float)L512;
    const float piInv512L = 3.14159265358979f * inv512L;
    const int sgn = (tauv & 1) ? -1 : 1;
    const int stp = sgn << 9;                       // +-512 per t
    const int dnc = sgn * (KSPLIT * 64 * 512);      // +-131072 per chunk (<=256L)

    // initial nd = sgn*(512*t_first - tau*L), reduced mod 512L to (-256L, 256L]
    int n0 = sgn * (512 * (h * 64 + tb8) - tauv * L);
    {
        const int q = (int)rintf((float)n0 * inv512L);
        n0 -= q * L512;
        if (n0 <= -L256) n0 += L512;
        if (n0 >   L256) n0 -= L512;
    }

    const int nc = (L + 63) >> 6;

    f32x4 acc0 = {0.f, 0.f, 0.f, 0.f};
    f32x4 acc1 = {0.f, 0.f, 0.f, 0.f};

    int4 pf0, pf1;
    {
        const unsigned short* g = gsrcBase + h * 64;
        pf0 = *(const int4*)(g);
        pf1 = *(const int4*)(g + 32);
    }

    for (int s = h; s < nc; s += KSPLIT) {
        const int t0 = s << 6;
        __syncthreads();                            // prev MFMA done / tab ready

        *(int4*)&A_lds[wid][0][lane][0] = pf0;
        *(int4*)&A_lds[wid][1][lane][0] = pf1;

        if (s + KSPLIT < nc) {
            const unsigned short* g = gsrcBase + (t0 + KSPLIT * 64);
            pf0 = *(const int4*)(g);
            pf1 = *(const int4*)(g + 32);
        }

        // ---- build M chunk: 8 entries/thread ----
        {
            float sv[8];
            *(float4*)&sv[0] = *(const float4*)&tab[t0 + tb8];      // ds_read_b128
            *(float4*)&sv[4] = *(const float4*)&tab[t0 + tb8 + 4];  // (broadcast)
            const int tlim = L - (t0 + tb8);        // d < tlim -> t valid
            int nd = n0;
            union { short s[8]; int4 v; } pk;
            #pragma unroll
            for (int d = 0; d < 8; ++d) {
                const float nf = (float)nd;
                const float w  = nf * piInv512L;    // pi*u
                const float ru = __builtin_amdgcn_rcpf(w);
                const float u  = nf * inv512L;
                const float u2 = u * u;
                const float p  = fmaf(u2, fmaf(u2, -0.64766070f, -0.68902837f),
                                      -1.04719755f);
                const float cotv = fmaf(u, p, ru);
                float Mv = sv[d] * cotv;
                Mv = (nd == 0) ? ((d < tlim) ? 1.0f : 0.0f) : Mv;  // rare singular
                pk.s[d] = f2bf(Mv);
                nd += stp;
                if (nd >  L256)  nd -= L512;
                if (nd <= -L256) nd += L512;
            }
            *(int4*)&B_lds[jB][ksubB][laneB][0] = pk.v;
        }

        n0 += dnc;
        if (n0 >  L256)  n0 -= L512;
        if (n0 <= -L256) n0 += L512;

        __syncthreads();

        const bf16x8 a0  = *(const bf16x8*)&A_lds[wid][0][lane][0];
        const bf16x8 a1  = *(const bf16x8*)&A_lds[wid][1][lane][0];
        const bf16x8 b00 = *(const bf16x8*)&B_lds[0][0][lane][0];
        const bf16x8 b01 = *(const bf16x8*)&B_lds[0][1][lane][0];
        const bf16x8 b10 = *(const bf16x8*)&B_lds[1][0][lane][0];
        const bf16x8 b11 = *(const bf16x8*)&B_lds[1][1][lane][0];
        acc0 = __builtin_amdgcn_mfma_f32_16x16x32_bf16(a0, b00, acc0, 0, 0, 0);
        acc0 = __builtin_amdgcn_mfma_f32_16x16x32_bf16(a1, b01, acc0, 0, 0, 0);
        acc1 = __builtin_amdgcn_mfma_f32_16x16x32_bf16(a0, b10, acc1, 0, 0, 0);
        acc1 = __builtin_amdgcn_mfma_f32_16x16x32_bf16(a1, b11, acc1, 0, 0, 0);
    }

    // ---- epilogue: atomic accumulate this h-partial into out ----
    {
        float* ob = out + ((size_t)b * C_CH + wid * 16 + ((lane >> 4) << 2)) * OUT_LEN
                        + tau0 + (lane & 15);
        #pragma unroll
        for (int r = 0; r < 4; ++r) {
            unsafeAtomicAdd(&ob[(size_t)r * OUT_LEN],      acc0[r]);
            unsafeAtomicAdd(&ob[(size_t)r * OUT_LEN + 16], acc1[r]);
        }
    }
}

// ---------------------------------------------------------------------------
// Monolithic fallback (round-1, known-correct) if ws too small.
// ---------------------------------------------------------------------------
__global__ __launch_bounds__(256) void spectral_pool_mono(
    const float* __restrict__ x, const int* __restrict__ length,
    float* __restrict__ out)
{
    const int bc  = blockIdx.x;
    const int b   = bc >> 6;
    const int tid = threadIdx.x;
    const int L   = length[b];

    const float* __restrict__ xrow = x + (size_t)bc * T_IN;
    float* __restrict__ orow = out + (size_t)bc * OUT_LEN;

    if (L < OUT_LEN) {
        for (int t = tid; t < OUT_LEN; t += 256)
            orow[t] = (t < L) ? xrow[t] : 0.0f;
        return;
    }

    __shared__ float xs[T_IN];
    __shared__ float Xr[257];
    __shared__ float Xi[257];
    __shared__ float red[256];

    {
        const float4* __restrict__ src = (const float4*)xrow;
        float4* dst = (float4*)xs;
        #pragma unroll
        for (int i = 0; i < T_IN / 4 / 256; ++i)
            dst[tid + i * 256] = src[tid + i * 256];
    }
    __syncthreads();

    const float twoPi = 6.28318530717958647692f;
    const float fL = (float)L;

    {
        const int k = tid;
        float s, co;
        sincosf(-twoPi * (float)k / fL, &s, &co);
        float zr = 1.0f, zi = 0.0f;
        float arr = 0.0f, aii = 0.0f;
        for (int t = 0; t < L; ++t) {
            const float xv = xs[t];
            arr = fmaf(xv, zr, arr);
            aii = fmaf(xv, zi, aii);
            const float nzr = fmaf(zr, co, -zi * s);
            const float nzi = fmaf(zr, s,   zi * co);
            zr = nzr; zi = nzi;
        }
        Xr[k] = arr;
        Xi[k] = aii;
    }
    {
        float part = 0.0f;
        for (int t = tid; t < L; t += 256) {
            const int m = (256 * t) % L;
            part = fmaf(xs[t], cosf(-twoPi * (float)m / fL), part);
        }
        red[tid] = part;
    }
    __syncthreads();
    #pragma unroll
    for (int sft = 128; sft > 0; sft >>= 1) {
        if (tid < sft) red[tid] += red[tid + sft];
        __syncthreads();
    }
    if (tid == 0) { Xr[256] = red[0]; Xi[256] = 0.0f; }
    __syncthreads();
    {
        const int t = tid;
        float s, co;
        sincosf(twoPi * (float)t / 512.0f, &s, &co);
        float zr = co, zi = s;
        float accE = 0.0f, accO = 0.0f;
        #pragma unroll 2
        for (int k = 1; k < 256; ++k) {
            const float re = fmaf(Xr[k], zr, -Xi[k] * zi);
            if (k & 1) accO += re; else accE += re;
            const float nzr = fmaf(zr, co, -zi * s);
            const float nzi = fmaf(zr, s,   zi * co);
            zr = nzr; zi = nzi;
        }
        const float base = Xr[0] + ((t & 1) ? -Xr[256] : Xr[256]);
        const float invN = 1.0f / 512.0f;
        orow[t]       = (base + 2.0f * (accE + accO)) * invN;
        orow[t + 256] = (base + 2.0f * (accE - accO)) * invN;
    }
}

extern "C" void kernel_launch(void* const* d_in, const int* in_sizes, int n_in,
                              void* d_out, int out_size, void* d_ws, size_t ws_size,
                              hipStream_t stream) {
    const float* x      = (const float*)d_in[0];
    const int*   length = (const int*)d_in[1];
    float*       out    = (float*)d_out;
    const int B = in_sizes[1];

    const size_t xbf_bytes = (size_t)B * C_CH * T_IN * 2;   // 4 MB

    if (ws_size >= xbf_bytes) {
        unsigned short* xbf = (unsigned short*)d_ws;
        const int total8 = B * C_CH * T_IN / 8;
        hipLaunchKernelGGL(prep_kernel, dim3((total8 + 255) / 256), dim3(256),
                           0, stream, x, length, xbf, out, B);
        hipLaunchKernelGGL(spectral_gemm, dim3(B * NTT * KSPLIT), dim3(256),
                           0, stream, xbf, length, out, B);
    } else {
        hipLaunchKernelGGL(spectral_pool_mono, dim3(B * C_CH), dim3(256), 0, stream,
                           x, length, out);
    }
}

// Round 6
// 18.671 us; speedup vs baseline: 3.4047x; 1.0657x over previous
//
#include <hip/hip_runtime.h>
#include <hip/hip_bf16.h>
#include <math.h>

#define OUT_LEN 512
#define T_IN    2048
#define C_CH    64
#define BN      32
#define NTT     (OUT_LEN / BN)   // 16 tau-tiles
#define KSPLIT  4

typedef __attribute__((ext_vector_type(8))) short bf16x8;
typedef __attribute__((ext_vector_type(4))) float f32x4;

static __device__ __forceinline__ short f2bf(float f) {
    unsigned int u = __float_as_uint(f);
    unsigned int r = (u + 0x7FFFu + ((u >> 16) & 1u)) >> 16;   // RNE
    return (short)r;
}

// ---------------------------------------------------------------------------
// K0: fused prep.
//  - convert x (f32) -> xbf (bf16), 8 elems/thread
//  - init out: zeros for L>=512 batches, masked copy for L<512
// ---------------------------------------------------------------------------
__global__ __launch_bounds__(256) void prep_kernel(
    const float* __restrict__ x, const int* __restrict__ length,
    unsigned short* __restrict__ xbf, float* __restrict__ out, int B)
{
    const int idx = blockIdx.x * 256 + threadIdx.x;
    const int total8 = B * C_CH * T_IN / 8;
    if (idx < total8) {
        const float4 v0 = ((const float4*)x)[2 * idx];
        const float4 v1 = ((const float4*)x)[2 * idx + 1];
        union { short s[8]; int4 v; } pk;
        pk.s[0] = f2bf(v0.x); pk.s[1] = f2bf(v0.y);
        pk.s[2] = f2bf(v0.z); pk.s[3] = f2bf(v0.w);
        pk.s[4] = f2bf(v1.x); pk.s[5] = f2bf(v1.y);
        pk.s[6] = f2bf(v1.z); pk.s[7] = f2bf(v1.w);
        ((int4*)xbf)[idx] = pk.v;
    }
    const int outq = B * C_CH * (OUT_LEN / 4);
    if (idx < outq) {
        const int b = idx >> 13;                    // 8192 float4 per batch
        const int L = length[b];
        float4 o = {0.f, 0.f, 0.f, 0.f};
        if (L < OUT_LEN) {
            const int t4 = idx & (OUT_LEN / 4 - 1);
            const int c  = (idx >> 7) & (C_CH - 1);
            const int t  = t4 * 4;
            const float4 v = *(const float4*)(x + ((size_t)b * C_CH + c) * T_IN + t);
            o.x = (t + 0 < L) ? v.x : 0.0f;
            o.y = (t + 1 < L) ? v.y : 0.0f;
            o.z = (t + 2 < L) ? v.z : 0.0f;
            o.w = (t + 3 < L) ? v.w : 0.0f;
        }
        ((float4*)out)[idx] = o;
    }
}

// ---------------------------------------------------------------------------
// K1: GEMM with on-the-fly M, atomic accumulation into out.
// M_L[t][tau] = sin(pi*n/L) * cot(pi*n/(512L)) / 512,  n = 512t - tau*L.
// sin term: (-1)^tau * tab[t] (per-block table, tail-masked, /512 folded);
// sign folds into the cot argument (n0 carries sgn). cot evaluated directly
// in w = pi*n/(512L) with a sign-agnostic one-step wrap w -= pi*rndne(w/pi);
// cot(w) ~ 1/w + w*(-1/3 - w^2/45 - 2 w^4/945), |w|<=pi/2.
// A-fragments live in registers (prefetch == fragment); B double-buffered in
// LDS with ONE barrier per K-step. Singular n==0 patched per-chunk (rare).
// ---------------------------------------------------------------------------
__global__ __launch_bounds__(256) void spectral_gemm(
    const unsigned short* __restrict__ xbf, const int* __restrict__ length,
    float* __restrict__ out, int B)
{
    const int bid = blockIdx.x;
    const int h   = bid & (KSPLIT - 1);
    const int rem = bid >> 2;
    const int tt  = rem % NTT;
    const int b   = rem / NTT;
    const int tid = threadIdx.x;
    const int L   = length[b];
    if (L < OUT_LEN) return;                        // prep wrote the copy branch

    const int tau0 = tt * BN;

    __shared__ short B_lds[2][2][2][64][8];         // [p][j][ksub][lane][i]
    __shared__ float tab[T_IN];

    // ---- tab[t] = sin(2*pi*(256t mod L)/L)/512, 0 for t>=L ----
    {
        const float invLf = 1.0f / (float)L;
        int q = (int)(65536.0f * invLf);
        int d256 = 65536 - q * L;                   // 65536 mod L
        if (d256 < 0)  d256 += L;
        if (d256 >= L) d256 -= L;
        const int v = tid << 8;                     // 256*tid
        q = (int)((float)v * invLf);
        int m = v - q * L;
        if (m < 0)  m += L;
        if (m >= L) m -= L;
        for (int i = tid; i < T_IN; i += 256) {
            tab[i] = (i < L)
                ? __builtin_amdgcn_sinf((float)m * invLf) * 0.001953125f : 0.0f;
            m += d256; if (m >= L) m -= L;
        }
    }

    // ---- A role: global fragment pointer (regs == fragment, no LDS) ----
    const int lane = tid & 63;
    const int wid  = tid >> 6;
    const unsigned short* gsrc =
        xbf + ((size_t)(b * C_CH + wid * 16 + (lane & 15))) * T_IN + ((lane >> 4) * 8);

    // ---- B-build role ----
    const int tau_l = tid & 31;
    const int tauv  = tau0 + tau_l;
    const int tb8   = (tid >> 5) << 3;              // 0,8,...,56
    const int jB    = tau_l >> 4;
    const int gB    = (tb8 >> 3) & 3;
    const int ksubB = tb8 >> 5;
    const int laneB = (tau_l & 15) + (gB << 4);

    const int L256 = L << 8;
    const int L512 = L << 9;
    const float inv512L   = 1.0f / (float)L512;
    const float piInv512L = 3.14159265358979f * inv512L;
    const int sgn = (tauv & 1) ? -1 : 1;
    const int dnc = sgn * (KSPLIT * 64 * 512);      // chunk advance (t += 256)
    const float stpf = (float)(sgn << 9);           // +-512 per t

    // initial n0 = sgn*(512*t_first - tau*L), reduced mod 512L to (-256L, 256L]
    int n0 = sgn * (512 * (h * 64 + tb8) - tauv * L);
    {
        const int q = (int)rintf((float)n0 * inv512L);
        n0 -= q * L512;
        if (n0 <= -L256) n0 += L512;
        if (n0 >   L256) n0 -= L512;
    }

    const int nc = (L + 63) >> 6;

    f32x4 acc0 = {0.f, 0.f, 0.f, 0.f};
    f32x4 acc1 = {0.f, 0.f, 0.f, 0.f};

    // prologue A prefetch (issue before tab barrier to hide HBM latency)
    int4 pf0, pf1;
    {
        const unsigned short* g = gsrc + (h << 6);
        pf0 = *(const int4*)(g);
        pf1 = *(const int4*)(g + 32);
    }

    // M-chunk builder: 8 entries/thread into B_lds[pp], advances n0.
    auto BUILD = [&](int pp, int ss) {
        const int t0 = ss << 6;
        float sv0[4], sv1[4];
        *(float4*)sv0 = *(const float4*)&tab[t0 + tb8];       // broadcast b128
        *(float4*)sv1 = *(const float4*)&tab[t0 + tb8 + 4];
        const float n0f = (float)n0;                          // exact (<2^20)
        float Mv[8];
        #pragma unroll
        for (int d = 0; d < 8; ++d) {
            const float nf = fmaf((float)d, stpf, n0f);       // exact
            const float w  = nf * piInv512L;
            const float rW = rintf(w * 0.318309886183790672f);
            const float wp = fmaf(rW, -3.14159265358979f, w); // wrap to (-pi/2,pi/2]
            const float ru = __builtin_amdgcn_rcpf(wp);
            const float w2 = wp * wp;
            const float pq = fmaf(w2, fmaf(w2, -2.1164021e-3f, -2.2222222e-2f),
                                  -0.333333333f);
            const float cotv = fmaf(wp, pq, ru);
            Mv[d] = ((d < 4) ? sv0[d] : sv1[d - 4]) * cotv;
        }
        // rare singular fix: n hits 0 inside this chunk -> true M is 1 (t<L)
        const int negAn = (sgn > 0) ? -n0 : n0;
        if ((unsigned)negAn <= 3584u && (n0 & 511) == 0) {
            const int ds = negAn >> 9;
            const float fix = (t0 + tb8 + ds < L) ? 1.0f : 0.0f;
            #pragma unroll
            for (int d = 0; d < 8; ++d)                        // static idx only
                if (d == ds) Mv[d] = fix;
        }
        union { __hip_bfloat162 h2[4]; int4 v; } pk;
        #pragma unroll
        for (int e = 0; e < 4; ++e)
            pk.h2[e] = __float22bfloat162_rn(make_float2(Mv[2 * e], Mv[2 * e + 1]));
        *(int4*)&B_lds[pp][jB][ksubB][laneB][0] = pk.v;
        // advance chunk state
        n0 += dnc;
        if (n0 >  L256)  n0 -= L512;
        if (n0 <= -L256) n0 += L512;
    };

    __syncthreads();                                // tab visible
    BUILD(0, h);
    int p = 0;

    for (int s = h; s < nc; s += KSPLIT) {
        __syncthreads();                            // publishes B_lds[p]
        const int sn = s + KSPLIT;
        const bool more = (sn < nc);
        int4 nf0 = pf0, nf1 = pf1;
        if (more) {
            const unsigned short* g = gsrc + (sn << 6);
            nf0 = *(const int4*)(g);
            nf1 = *(const int4*)(g + 32);
        }
        const bf16x8 b00 = *(const bf16x8*)&B_lds[p][0][0][lane][0];
        const bf16x8 b01 = *(const bf16x8*)&B_lds[p][0][1][lane][0];
        const bf16x8 b10 = *(const bf16x8*)&B_lds[p][1][0][lane][0];
        const bf16x8 b11 = *(const bf16x8*)&B_lds[p][1][1][lane][0];
        if (more) BUILD(p ^ 1, sn);                 // overlaps MFMA across waves
        const bf16x8 a0 = *(const bf16x8*)&pf0;
        const bf16x8 a1 = *(const bf16x8*)&pf1;
        acc0 = __builtin_amdgcn_mfma_f32_16x16x32_bf16(a0, b00, acc0, 0, 0, 0);
        acc0 = __builtin_amdgcn_mfma_f32_16x16x32_bf16(a1, b01, acc0, 0, 0, 0);
        acc1 = __builtin_amdgcn_mfma_f32_16x16x32_bf16(a0, b10, acc1, 0, 0, 0);
        acc1 = __builtin_amdgcn_mfma_f32_16x16x32_bf16(a1, b11, acc1, 0, 0, 0);
        pf0 = nf0; pf1 = nf1;
        p ^= 1;
    }

    // ---- epilogue: atomic accumulate this h-partial into out ----
    {
        float* ob = out + ((size_t)b * C_CH + wid * 16 + ((lane >> 4) << 2)) * OUT_LEN
                        + tau0 + (lane & 15);
        #pragma unroll
        for (int r = 0; r < 4; ++r) {
            unsafeAtomicAdd(&ob[(size_t)r * OUT_LEN],      acc0[r]);
            unsafeAtomicAdd(&ob[(size_t)r * OUT_LEN + 16], acc1[r]);
        }
    }
}

// ---------------------------------------------------------------------------
// Monolithic fallback (round-1, known-correct) if ws too small.
// ---------------------------------------------------------------------------
__global__ __launch_bounds__(256) void spectral_pool_mono(
    const float* __restrict__ x, const int* __restrict__ length,
    float* __restrict__ out)
{
    const int bc  = blockIdx.x;
    const int b   = bc >> 6;
    const int tid = threadIdx.x;
    const int L   = length[b];

    const float* __restrict__ xrow = x + (size_t)bc * T_IN;
    float* __restrict__ orow = out + (size_t)bc * OUT_LEN;

    if (L < OUT_LEN) {
        for (int t = tid; t < OUT_LEN; t += 256)
            orow[t] = (t < L) ? xrow[t] : 0.0f;
        return;
    }

    __shared__ float xs[T_IN];
    __shared__ float Xr[257];
    __shared__ float Xi[257];
    __shared__ float red[256];

    {
        const float4* __restrict__ src = (const float4*)xrow;
        float4* dst = (float4*)xs;
        #pragma unroll
        for (int i = 0; i < T_IN / 4 / 256; ++i)
            dst[tid + i * 256] = src[tid + i * 256];
    }
    __syncthreads();

    const float twoPi = 6.28318530717958647692f;
    const float fL = (float)L;

    {
        const int k = tid;
        float s, co;
        sincosf(-twoPi * (float)k / fL, &s, &co);
        float zr = 1.0f, zi = 0.0f;
        float arr = 0.0f, aii = 0.0f;
        for (int t = 0; t < L; ++t) {
            const float xv = xs[t];
            arr = fmaf(xv, zr, arr);
            aii = fmaf(xv, zi, aii);
            const float nzr = fmaf(zr, co, -zi * s);
            const float nzi = fmaf(zr, s,   zi * co);
            zr = nzr; zi = nzi;
        }
        Xr[k] = arr;
        Xi[k] = aii;
    }
    {
        float part = 0.0f;
        for (int t = tid; t < L; t += 256) {
            const int m = (256 * t) % L;
            part = fmaf(xs[t], cosf(-twoPi * (float)m / fL), part);
        }
        red[tid] = part;
    }
    __syncthreads();
    #pragma unroll
    for (int sft = 128; sft > 0; sft >>= 1) {
        if (tid < sft) red[tid] += red[tid + sft];
        __syncthreads();
    }
    if (tid == 0) { Xr[256] = red[0]; Xi[256] = 0.0f; }
    __syncthreads();
    {
        const int t = tid;
        float s, co;
        sincosf(twoPi * (float)t / 512.0f, &s, &co);
        float zr = co, zi = s;
        float accE = 0.0f, accO = 0.0f;
        #pragma unroll 2
        for (int k = 1; k < 256; ++k) {
            const float re = fmaf(Xr[k], zr, -Xi[k] * zi);
            if (k & 1) accO += re; else accE += re;
            const float nzr = fmaf(zr, co, -zi * s);
            const float nzi = fmaf(zr, s,   zi * co);
            zr = nzr; zi = nzi;
        }
        const float base = Xr[0] + ((t & 1) ? -Xr[256] : Xr[256]);
        const float invN = 1.0f / 512.0f;
        orow[t]       = (base + 2.0f * (accE + accO)) * invN;
        orow[t + 256] = (base + 2.0f * (accE - accO)) * invN;
    }
}

extern "C" void kernel_launch(void* const* d_in, const int* in_sizes, int n_in,
                              void* d_out, int out_size, void* d_ws, size_t ws_size,
                              hipStream_t stream) {
    const float* x      = (const float*)d_in[0];
    const int*   length = (const int*)d_in[1];
    float*       out    = (float*)d_out;
    const int B = in_sizes[1];

    const size_t xbf_bytes = (size_t)B * C_CH * T_IN * 2;   // 4 MB

    if (ws_size >= xbf_bytes) {
        unsigned short* xbf = (unsigned short*)d_ws;
        const int total8 = B * C_CH * T_IN / 8;
        hipLaunchKernelGGL(prep_kernel, dim3((total8 + 255) / 256), dim3(256),
                           0, stream, x, length, xbf, out, B);
        hipLaunchKernelGGL(spectral_gemm, dim3(B * NTT * KSPLIT), dim3(256),
                           0, stream, xbf, length, out, B);
    } else {
        hipLaunchKernelGGL(spectral_pool_mono, dim3(B * C_CH), dim3(256), 0, stream,
                           x, length, out);
    }
}